// Round 1
// baseline (1013.202 us; speedup 1.0000x reference)
//
#include <hip/hip_runtime.h>
#include <cstdint>

#define NNODES 50000
#define NEDGES 800000
#define ETOT   (NEDGES + NNODES)
#define HEADS 4
#define CH 64
#define HC 256
#define INDIM 256
#define OUTDIM 64
#define NEG_SLOPE 0.2f
#define BN_EPS 1e-5f

// ---------------- CSR build (dst-sorted) ----------------

__global__ void hist_kernel(const int* __restrict__ ei, int* __restrict__ cnt) {
    int t = blockIdx.x * blockDim.x + threadIdx.x;
    if (t >= ETOT) return;
    int d = (t < NEDGES) ? ei[NEDGES + t] : (t - NEDGES);  // self-loops appended
    atomicAdd(&cnt[d], 1);
}

// Per-block exclusive scan of cnt -> row_off (block-local), blockSums[b] = block total.
__global__ void scan1_kernel(const int* __restrict__ cnt, int* __restrict__ row_off,
                             int* __restrict__ blockSums) {
    __shared__ int tsum[256];
    const int tid = threadIdx.x;
    const int base = blockIdx.x * 4096 + tid * 16;
    int local[16];
    int run = 0;
#pragma unroll
    for (int i = 0; i < 16; ++i) {
        int idx = base + i;
        int v = (idx < NNODES) ? cnt[idx] : 0;
        local[i] = run;
        run += v;
    }
    tsum[tid] = run;
    __syncthreads();
    for (int d = 1; d < 256; d <<= 1) {
        int v = (tid >= d) ? tsum[tid - d] : 0;
        __syncthreads();
        tsum[tid] += v;
        __syncthreads();
    }
    int excl = (tid == 0) ? 0 : tsum[tid - 1];
#pragma unroll
    for (int i = 0; i < 16; ++i) {
        int idx = base + i;
        if (idx < NNODES) row_off[idx] = excl + local[i];
    }
    if (tid == 0) blockSums[blockIdx.x] = tsum[255];
}

// Add cross-block prefix; also write `next` (scatter cursors) and row_off[N].
__global__ void scan2_kernel(int* __restrict__ row_off, const int* __restrict__ blockSums,
                             int* __restrict__ nxt) {
    __shared__ int sprefix;
    if (threadIdx.x == 0) {
        int p = 0;
        for (int b = 0; b < (int)blockIdx.x; ++b) p += blockSums[b];
        sprefix = p;
    }
    __syncthreads();
    int prefix = sprefix;
    int base = blockIdx.x * 4096 + threadIdx.x * 16;
#pragma unroll
    for (int i = 0; i < 16; ++i) {
        int idx = base + i;
        if (idx < NNODES) {
            int v = row_off[idx] + prefix;
            row_off[idx] = v;
            nxt[idx] = v;
        }
    }
    if (blockIdx.x == 0 && threadIdx.x == 0) row_off[NNODES] = ETOT;
}

__global__ void fill_csr_kernel(const int* __restrict__ ei, int* __restrict__ nxt,
                                int* __restrict__ csr_src, int* __restrict__ csr_dst) {
    int t = blockIdx.x * blockDim.x + threadIdx.x;
    if (t >= ETOT) return;
    int s, d;
    if (t < NEDGES) { s = ei[t]; d = ei[NEDGES + t]; }
    else            { s = d = t - NEDGES; }
    int pos = atomicAdd(&nxt[d], 1);
    csr_src[pos] = s;
    csr_dst[pos] = d;
}

// ---------------- fp32 tiled GEMM: C[M,Ncols] = A[M,K] @ B[K,Ncols] (+bias) ----------------
// BM=BN=64, BK=16, 256 threads, 4x4 per thread.

__global__ __launch_bounds__(256)
void sgemm_kernel(const float* __restrict__ A, const float* __restrict__ B,
                  float* __restrict__ C, const float* __restrict__ bias,
                  int M, int K, int Ncols) {
    __shared__ float As[16][64];
    __shared__ float Bs[16][64];
    const int tid = threadIdx.x;
    const int tx = tid & 15, ty = tid >> 4;
    const int rowBase = blockIdx.y * 64;
    const int colBase = blockIdx.x * 64;

    const int aRow = tid >> 2;        // 0..63
    const int aCol = (tid & 3) * 4;   // 0,4,8,12
    const int bRow = tid >> 4;        // 0..15
    const int bCol = (tid & 15) * 4;  // 0..60

    float acc[4][4] = {};

    for (int kt = 0; kt < K; kt += 16) {
        float4 av = make_float4(0.f, 0.f, 0.f, 0.f);
        int ar = rowBase + aRow;
        if (ar < M) av = *(const float4*)&A[(size_t)ar * K + kt + aCol];
        As[aCol + 0][aRow] = av.x;
        As[aCol + 1][aRow] = av.y;
        As[aCol + 2][aRow] = av.z;
        As[aCol + 3][aRow] = av.w;

        float4 bv = *(const float4*)&B[(size_t)(kt + bRow) * Ncols + colBase + bCol];
        *(float4*)&Bs[bRow][bCol] = bv;
        __syncthreads();

#pragma unroll
        for (int k = 0; k < 16; ++k) {
            float a[4], b[4];
#pragma unroll
            for (int i = 0; i < 4; ++i) a[i] = As[k][ty * 4 + i];
#pragma unroll
            for (int j = 0; j < 4; ++j) b[j] = Bs[k][tx * 4 + j];
#pragma unroll
            for (int i = 0; i < 4; ++i)
#pragma unroll
                for (int j = 0; j < 4; ++j)
                    acc[i][j] += a[i] * b[j];
        }
        __syncthreads();
    }

#pragma unroll
    for (int i = 0; i < 4; ++i) {
        int r = rowBase + ty * 4 + i;
        if (r >= M) continue;
#pragma unroll
        for (int j = 0; j < 4; ++j) {
            int c = colBase + tx * 4 + j;
            float v = acc[i][j];
            if (bias) v += bias[c];
            C[(size_t)r * Ncols + c] = v;
        }
    }
}

// ---------------- attention scalars ----------------

__global__ void alpha_kernel(const float* __restrict__ xh,
                             const float* __restrict__ att_src,
                             const float* __restrict__ att_dst,
                             float* __restrict__ as_, float* __restrict__ ad_) {
    int t = blockIdx.x * blockDim.x + threadIdx.x;  // over N*H
    if (t >= NNODES * HEADS) return;
    int n = t >> 2, h = t & 3;
    const float* xp = xh + (size_t)n * HC + h * CH;
    const float* sp = att_src + h * CH;
    const float* dp = att_dst + h * CH;
    float s = 0.f, d = 0.f;
#pragma unroll 8
    for (int c = 0; c < CH; ++c) {
        float v = xp[c];
        s += v * sp[c];
        d += v * dp[c];
    }
    as_[t] = s;
    ad_[t] = d;
}

// ex[e][h] = exp(leaky_relu(as[src]+ad[dst]))  (CSR edge order; no max-shift needed,
// |e| is small by construction so exp cannot overflow; softmax is shift-invariant)
__global__ void edge_ex_kernel(const int* __restrict__ csr_src, const int* __restrict__ csr_dst,
                               const float* __restrict__ as_, const float* __restrict__ ad_,
                               float* __restrict__ ex) {
    int e = blockIdx.x * blockDim.x + threadIdx.x;
    if (e >= ETOT) return;
    int s = csr_src[e], d = csr_dst[e];
    float4 a = *(const float4*)&as_[s * 4];
    float4 b = *(const float4*)&ad_[d * 4];
    float4 r;
    float v;
    v = a.x + b.x; v = v > 0.f ? v : NEG_SLOPE * v; r.x = expf(v);
    v = a.y + b.y; v = v > 0.f ? v : NEG_SLOPE * v; r.y = expf(v);
    v = a.z + b.z; v = v > 0.f ? v : NEG_SLOPE * v; r.z = expf(v);
    v = a.w + b.w; v = v > 0.f ? v : NEG_SLOPE * v; r.w = expf(v);
    *(float4*)&ex[e * 4] = r;
}

// one block (256 thr = 256 channels) per dst node; no atomics.
__global__ __launch_bounds__(256)
void aggregate_kernel(const int* __restrict__ row_off, const int* __restrict__ csr_src,
                      const float* __restrict__ ex, const float* __restrict__ xh,
                      const float* __restrict__ bias, float* __restrict__ out) {
    int d = blockIdx.x;
    int c = threadIdx.x;
    int h = c >> 6;
    int start = row_off[d], end = row_off[d + 1];
    float acc = 0.f, den = 0.f;
    for (int e = start; e < end; ++e) {
        int s = csr_src[e];
        float w = ex[e * 4 + h];
        den += w;
        acc += w * xh[(size_t)s * HC + c];
    }
    out[(size_t)d * HC + c] = acc / (den + 1e-16f) + bias[c];
}

// ---------------- BatchNorm (biased var, matching x.var()) ----------------

__global__ void bn_stats_kernel(const float* __restrict__ x, float* __restrict__ sums,
                                float* __restrict__ sumsq) {
    int j = threadIdx.x;  // 256 columns
    int r0 = blockIdx.x * 128;
    int r1 = min(r0 + 128, NNODES);
    float s = 0.f, s2 = 0.f;
    for (int r = r0; r < r1; ++r) {
        float v = x[(size_t)r * HC + j];
        s += v;
        s2 += v * v;
    }
    atomicAdd(&sums[j], s);
    atomicAdd(&sumsq[j], s2);
}

__global__ void bn_apply_kernel(float* __restrict__ x, const float* __restrict__ sums,
                                const float* __restrict__ sumsq, const float* __restrict__ g,
                                const float* __restrict__ beta) {
    int t = blockIdx.x * blockDim.x + threadIdx.x;  // over N*HC
    if (t >= NNODES * HC) return;
    int j = t & (HC - 1);
    float mu = sums[j] * (1.f / NNODES);
    float var = sumsq[j] * (1.f / NNODES) - mu * mu;
    x[t] = (x[t] - mu) * rsqrtf(var + BN_EPS) * g[j] + beta[j];
}

// ---------------- log_softmax over 64 cols: one wave per row ----------------

__global__ void logsoftmax_kernel(const float* __restrict__ emb, float* __restrict__ out) {
    int row = blockIdx.x * 4 + (threadIdx.x >> 6);
    int lane = threadIdx.x & 63;
    float v = emb[(size_t)row * OUTDIM + lane];
    float m = v;
    for (int off = 32; off > 0; off >>= 1) m = fmaxf(m, __shfl_xor(m, off, 64));
    float e = expf(v - m);
    float s = e;
    for (int off = 32; off > 0; off >>= 1) s += __shfl_xor(s, off, 64);
    out[(size_t)row * OUTDIM + lane] = v - m - logf(s);
}

// ---------------- launch ----------------

extern "C" void kernel_launch(void* const* d_in, const int* in_sizes, int n_in,
                              void* d_out, int out_size, void* d_ws, size_t ws_size,
                              hipStream_t stream) {
    const float* x   = (const float*)d_in[0];
    const int*   ei  = (const int*)d_in[1];
    const float* W1  = (const float*)d_in[2];
    const float* at_s1 = (const float*)d_in[3];
    const float* at_d1 = (const float*)d_in[4];
    const float* b1  = (const float*)d_in[5];
    const float* W2  = (const float*)d_in[6];
    const float* at_s2 = (const float*)d_in[7];
    const float* at_d2 = (const float*)d_in[8];
    const float* b2  = (const float*)d_in[9];
    const float* g1  = (const float*)d_in[10];
    const float* be1 = (const float*)d_in[11];
    const float* g2  = (const float*)d_in[12];
    const float* be2 = (const float*)d_in[13];
    const float* Wl  = (const float*)d_in[14];
    const float* bl  = (const float*)d_in[15];

    float* out = (float*)d_out;                        // [N, 64] log_softmax
    float* emb = out + (size_t)NNODES * OUTDIM;        // [N, 64] emb (output 1)

    char* ws = (char*)d_ws;
    size_t off = 0;
    auto alloc = [&](size_t bytes) {
        void* p = ws + off;
        off += (bytes + 255) & ~(size_t)255;
        return p;
    };
    int*   cnt     = (int*)alloc((size_t)NNODES * 4);
    int*   row_off = (int*)alloc((size_t)(NNODES + 1) * 4);
    int*   nxt     = (int*)alloc((size_t)NNODES * 4);
    int*   bsums   = (int*)alloc(64 * 4);
    int*   csr_src = (int*)alloc((size_t)ETOT * 4);
    int*   csr_dst = (int*)alloc((size_t)ETOT * 4);
    float* ex      = (float*)alloc((size_t)ETOT * 4 * 4);
    float* asrc    = (float*)alloc((size_t)NNODES * 4 * 4);
    float* adst    = (float*)alloc((size_t)NNODES * 4 * 4);
    float* xh      = (float*)alloc((size_t)NNODES * HC * 4);
    float* hbuf    = (float*)alloc((size_t)NNODES * HC * 4);
    float* bnsum   = (float*)alloc(HC * 4);
    float* bnsq    = (float*)alloc(HC * 4);

    const int scanBlocks = (NNODES + 4095) / 4096;  // 13
    const int eBlocks = (ETOT + 255) / 256;

    // ---- CSR build (shared by both layers) ----
    hipMemsetAsync(cnt, 0, (size_t)NNODES * 4, stream);
    hist_kernel<<<eBlocks, 256, 0, stream>>>(ei, cnt);
    scan1_kernel<<<scanBlocks, 256, 0, stream>>>(cnt, row_off, bsums);
    scan2_kernel<<<scanBlocks, 256, 0, stream>>>(row_off, bsums, nxt);
    fill_csr_kernel<<<eBlocks, 256, 0, stream>>>(ei, nxt, csr_src, csr_dst);

    dim3 gemmGrid((HC + 63) / 64, (NNODES + 63) / 64);
    int nhBlocks = (NNODES * HEADS + 255) / 256;
    int elemBlocks = (NNODES * HC + 255) / 256;
    int statBlocks = (NNODES + 127) / 128;

    // ---- Layer 1 ----
    sgemm_kernel<<<gemmGrid, 256, 0, stream>>>(x, W1, xh, nullptr, NNODES, INDIM, HC);
    alpha_kernel<<<nhBlocks, 256, 0, stream>>>(xh, at_s1, at_d1, asrc, adst);
    edge_ex_kernel<<<eBlocks, 256, 0, stream>>>(csr_src, csr_dst, asrc, adst, ex);
    aggregate_kernel<<<NNODES, 256, 0, stream>>>(row_off, csr_src, ex, xh, b1, hbuf);
    hipMemsetAsync(bnsum, 0, HC * 4, stream);
    hipMemsetAsync(bnsq, 0, HC * 4, stream);
    bn_stats_kernel<<<statBlocks, HC, 0, stream>>>(hbuf, bnsum, bnsq);
    bn_apply_kernel<<<elemBlocks, 256, 0, stream>>>(hbuf, bnsum, bnsq, g1, be1);

    // ---- Layer 2 ----
    sgemm_kernel<<<gemmGrid, 256, 0, stream>>>(hbuf, W2, xh, nullptr, NNODES, HC, HC);
    alpha_kernel<<<nhBlocks, 256, 0, stream>>>(xh, at_s2, at_d2, asrc, adst);
    edge_ex_kernel<<<eBlocks, 256, 0, stream>>>(csr_src, csr_dst, asrc, adst, ex);
    aggregate_kernel<<<NNODES, 256, 0, stream>>>(row_off, csr_src, ex, xh, b2, hbuf);
    hipMemsetAsync(bnsum, 0, HC * 4, stream);
    hipMemsetAsync(bnsq, 0, HC * 4, stream);
    bn_stats_kernel<<<statBlocks, HC, 0, stream>>>(hbuf, bnsum, bnsq);
    bn_apply_kernel<<<elemBlocks, 256, 0, stream>>>(hbuf, bnsum, bnsq, g2, be2);

    // ---- Final linear + log_softmax ----
    dim3 gemmGrid3((OUTDIM + 63) / 64, (NNODES + 63) / 64);
    sgemm_kernel<<<gemmGrid3, 256, 0, stream>>>(hbuf, Wl, emb, bl, NNODES, HC, OUTDIM);
    logsoftmax_kernel<<<NNODES / 4, 256, 0, stream>>>(emb, out);
}

// Round 2
// 599.596 us; speedup vs baseline: 1.6898x; 1.6898x over previous
//
#include <hip/hip_runtime.h>
#include <cstdint>

#define NNODES 50000
#define NEDGES 800000
#define ETOT   (NEDGES + NNODES)
#define HEADS 4
#define CH 64
#define HC 256
#define INDIM 256
#define OUTDIM 64
#define NEG_SLOPE 0.2f
#define BN_EPS 1e-5f

typedef unsigned short u16;
typedef __attribute__((ext_vector_type(8))) short short8;
typedef __attribute__((ext_vector_type(4))) float floatx4;

__device__ inline float bf2f(u16 u) {
    union { unsigned int i; float f; } c;
    c.i = ((unsigned int)u) << 16;
    return c.f;
}
__device__ inline u16 f2bf(float f) {
    union { float f; unsigned int i; } c;
    c.f = f;
    unsigned int u = c.i + 0x7fff + ((c.i >> 16) & 1);
    return (u16)(u >> 16);
}
__device__ inline void async16(u16* lds, const u16* g) {
    __builtin_amdgcn_global_load_lds(
        (const __attribute__((address_space(1))) unsigned int*)g,
        (__attribute__((address_space(3))) unsigned int*)lds,
        16, 0, 0);
}

// ---------------- CSR build (dst-sorted) ----------------

__global__ void hist_kernel(const int* __restrict__ ei, int* __restrict__ cnt) {
    int t = blockIdx.x * blockDim.x + threadIdx.x;
    if (t >= ETOT) return;
    int d = (t < NEDGES) ? ei[NEDGES + t] : (t - NEDGES);
    atomicAdd(&cnt[d], 1);
}

__global__ void scan1_kernel(const int* __restrict__ cnt, int* __restrict__ row_off,
                             int* __restrict__ blockSums) {
    __shared__ int tsum[256];
    const int tid = threadIdx.x;
    const int base = blockIdx.x * 4096 + tid * 16;
    int local[16];
    int run = 0;
#pragma unroll
    for (int i = 0; i < 16; ++i) {
        int idx = base + i;
        int v = (idx < NNODES) ? cnt[idx] : 0;
        local[i] = run;
        run += v;
    }
    tsum[tid] = run;
    __syncthreads();
    for (int d = 1; d < 256; d <<= 1) {
        int v = (tid >= d) ? tsum[tid - d] : 0;
        __syncthreads();
        tsum[tid] += v;
        __syncthreads();
    }
    int excl = (tid == 0) ? 0 : tsum[tid - 1];
#pragma unroll
    for (int i = 0; i < 16; ++i) {
        int idx = base + i;
        if (idx < NNODES) row_off[idx] = excl + local[i];
    }
    if (tid == 0) blockSums[blockIdx.x] = tsum[255];
}

__global__ void scan2_kernel(int* __restrict__ row_off, const int* __restrict__ blockSums,
                             int* __restrict__ nxt) {
    __shared__ int sprefix;
    if (threadIdx.x == 0) {
        int p = 0;
        for (int b = 0; b < (int)blockIdx.x; ++b) p += blockSums[b];
        sprefix = p;
    }
    __syncthreads();
    int prefix = sprefix;
    int base = blockIdx.x * 4096 + threadIdx.x * 16;
#pragma unroll
    for (int i = 0; i < 16; ++i) {
        int idx = base + i;
        if (idx < NNODES) {
            int v = row_off[idx] + prefix;
            row_off[idx] = v;
            nxt[idx] = v;
        }
    }
    if (blockIdx.x == 0 && threadIdx.x == 0) row_off[NNODES] = ETOT;
}

__global__ void fill_csr_kernel(const int* __restrict__ ei, int* __restrict__ nxt,
                                int* __restrict__ csr_src) {
    int t = blockIdx.x * blockDim.x + threadIdx.x;
    if (t >= ETOT) return;
    int s, d;
    if (t < NEDGES) { s = ei[t]; d = ei[NEDGES + t]; }
    else            { s = d = t - NEDGES; }
    int pos = atomicAdd(&nxt[d], 1);
    csr_src[pos] = s;
}

// ---------------- casts ----------------

__global__ void castx_kernel(const float* __restrict__ x, u16* __restrict__ xb, int n4) {
    int t = blockIdx.x * blockDim.x + threadIdx.x;
    if (t >= n4) return;
    float4 v = *(const float4*)&x[(size_t)t * 4];
    ushort4 o;
    o.x = f2bf(v.x); o.y = f2bf(v.y); o.z = f2bf(v.z); o.w = f2bf(v.w);
    *(ushort4*)&xb[(size_t)t * 4] = o;
}

// W [K][Ncols] fp32 -> Wt [Ncols][K] bf16
__global__ void wcast_kernel(const float* __restrict__ W, u16* __restrict__ Wt,
                             int K, int Ncols) {
    int t = blockIdx.x * blockDim.x + threadIdx.x;
    if (t >= K * Ncols) return;
    int k = t / Ncols, n = t - k * Ncols;
    Wt[n * K + k] = f2bf(W[t]);
}

// ---------------- bf16 MFMA GEMM: C[M,Ncols] = A[M,K] @ Bt[Ncols,K]^T ----------------
// BM=BN=128, BK=32, 256 threads (4 waves 2x2, each 64x64 via 4x4 MFMA 16x16x32).

__global__ __launch_bounds__(256)
void gemm_bf16_kernel(const u16* __restrict__ A, const u16* __restrict__ Bt,
                      u16* __restrict__ Cbf, float* __restrict__ Cf,
                      const float* __restrict__ bias, int M, int Ncols, int K) {
    __shared__ u16 As[128 * 32];
    __shared__ u16 Bs[128 * 32];
    const int tid = threadIdx.x;
    const int wave = tid >> 6, lane = tid & 63;
    const int q15 = lane & 15, quad = lane >> 4;
    const int rowBase = blockIdx.y * 128;
    const int colBase = blockIdx.x * 128;
    const int waveM = (wave >> 1) * 64, waveN = (wave & 1) * 64;

    floatx4 acc[4][4];
    floatx4 zero = {0.f, 0.f, 0.f, 0.f};
#pragma unroll
    for (int i = 0; i < 4; ++i)
#pragma unroll
        for (int j = 0; j < 4; ++j) acc[i][j] = zero;

    for (int kt = 0; kt < K; kt += 32) {
#pragma unroll
        for (int q = 0; q < 2; ++q) {
            int e8 = (wave * 2 + q) * 64 + lane;   // 0..511 (8 bf16 each)
            int r = e8 >> 2;
            int c = (e8 & 3) * 8;
            int ar = rowBase + r; if (ar >= M) ar = M - 1;
            async16(&As[(wave * 2 + q) * 512], &A[(size_t)ar * K + kt + c]);
            int br = colBase + r; if (br >= Ncols) br = Ncols - 1;
            async16(&Bs[(wave * 2 + q) * 512], &Bt[(size_t)br * K + kt + c]);
        }
        __syncthreads();

        short8 af[4], bfr[4];
#pragma unroll
        for (int i = 0; i < 4; ++i)
            af[i] = *(const short8*)&As[(waveM + i * 16 + q15) * 32 + quad * 8];
#pragma unroll
        for (int j = 0; j < 4; ++j)
            bfr[j] = *(const short8*)&Bs[(waveN + j * 16 + q15) * 32 + quad * 8];
#pragma unroll
        for (int i = 0; i < 4; ++i)
#pragma unroll
            for (int j = 0; j < 4; ++j)
                acc[i][j] = __builtin_amdgcn_mfma_f32_16x16x32_bf16(af[i], bfr[j], acc[i][j], 0, 0, 0);
        __syncthreads();
    }

#pragma unroll
    for (int i = 0; i < 4; ++i) {
#pragma unroll
        for (int j = 0; j < 4; ++j) {
            int gcol = colBase + waveN + j * 16 + q15;
            if (gcol >= Ncols) continue;
#pragma unroll
            for (int r = 0; r < 4; ++r) {
                int grow = rowBase + waveM + i * 16 + quad * 4 + r;
                if (grow >= M) continue;
                float v = acc[i][j][r];
                if (bias) v += bias[gcol];
                if (Cf)  Cf[(size_t)grow * Ncols + gcol] = v;
                if (Cbf) Cbf[(size_t)grow * Ncols + gcol] = f2bf(v);
            }
        }
    }
}

// ---------------- attention scalars (from bf16 features) ----------------

__global__ void alpha_kernel(const u16* __restrict__ xh,
                             const float* __restrict__ att_src,
                             const float* __restrict__ att_dst,
                             float* __restrict__ as_, float* __restrict__ ad_) {
    int t = blockIdx.x * blockDim.x + threadIdx.x;  // over N*H
    if (t >= NNODES * HEADS) return;
    int n = t >> 2, h = t & 3;
    const u16* xp = xh + (size_t)n * HC + h * CH;
    const float* sp = att_src + h * CH;
    const float* dp = att_dst + h * CH;
    float s = 0.f, d = 0.f;
#pragma unroll
    for (int c = 0; c < CH; c += 4) {
        ushort4 xv = *(const ushort4*)&xp[c];
        float v0 = bf2f(xv.x), v1 = bf2f(xv.y), v2 = bf2f(xv.z), v3 = bf2f(xv.w);
        s += v0 * sp[c] + v1 * sp[c + 1] + v2 * sp[c + 2] + v3 * sp[c + 3];
        d += v0 * dp[c] + v1 * dp[c + 1] + v2 * dp[c + 2] + v3 * dp[c + 3];
    }
    as_[t] = s;
    ad_[t] = d;
}

// ---------------- fused softmax+aggregate: 4 dst nodes / block, 64 lanes each ----------------

__global__ __launch_bounds__(256)
void aggregate_kernel(const int* __restrict__ row_off, const int* __restrict__ csr_src,
                      const float* __restrict__ asrc, const float* __restrict__ adst,
                      const u16* __restrict__ xh, const float* __restrict__ bias,
                      u16* __restrict__ out) {
    const int g = threadIdx.x >> 6;
    const int lane = threadIdx.x & 63;
    const int d = blockIdx.x * 4 + g;
    const int h = lane >> 4;
    const int cbase = lane * 4;
    const float adt = adst[d * 4 + h];
    int start = row_off[d], end = row_off[d + 1];
    float a0 = 0.f, a1 = 0.f, a2 = 0.f, a3 = 0.f, den = 0.f;
    int e = start;
    for (; e + 1 < end; e += 2) {
        int s0 = csr_src[e], s1 = csr_src[e + 1];
        float v0 = asrc[s0 * 4 + h] + adt;
        float v1 = asrc[s1 * 4 + h] + adt;
        ushort4 x0 = *(const ushort4*)&xh[(size_t)s0 * HC + cbase];
        ushort4 x1 = *(const ushort4*)&xh[(size_t)s1 * HC + cbase];
        v0 = v0 > 0.f ? v0 : NEG_SLOPE * v0;
        v1 = v1 > 0.f ? v1 : NEG_SLOPE * v1;
        float w0 = __expf(v0), w1 = __expf(v1);
        den += w0 + w1;
        a0 += w0 * bf2f(x0.x) + w1 * bf2f(x1.x);
        a1 += w0 * bf2f(x0.y) + w1 * bf2f(x1.y);
        a2 += w0 * bf2f(x0.z) + w1 * bf2f(x1.z);
        a3 += w0 * bf2f(x0.w) + w1 * bf2f(x1.w);
    }
    if (e < end) {
        int s0 = csr_src[e];
        float v0 = asrc[s0 * 4 + h] + adt;
        ushort4 x0 = *(const ushort4*)&xh[(size_t)s0 * HC + cbase];
        v0 = v0 > 0.f ? v0 : NEG_SLOPE * v0;
        float w0 = __expf(v0);
        den += w0;
        a0 += w0 * bf2f(x0.x);
        a1 += w0 * bf2f(x0.y);
        a2 += w0 * bf2f(x0.z);
        a3 += w0 * bf2f(x0.w);
    }
    float inv = 1.f / (den + 1e-16f);
    ushort4 o;
    o.x = f2bf(a0 * inv + bias[cbase + 0]);
    o.y = f2bf(a1 * inv + bias[cbase + 1]);
    o.z = f2bf(a2 * inv + bias[cbase + 2]);
    o.w = f2bf(a3 * inv + bias[cbase + 3]);
    *(ushort4*)&out[(size_t)d * HC + cbase] = o;
}

// ---------------- BatchNorm on bf16 buffers (fp32 accumulation) ----------------

__global__ void bn_stats_kernel(const u16* __restrict__ x, float* __restrict__ sums,
                                float* __restrict__ sumsq) {
    int j = threadIdx.x;  // 256 columns
    int r0 = blockIdx.x * 128;
    int r1 = min(r0 + 128, NNODES);
    float s = 0.f, s2 = 0.f;
    for (int r = r0; r < r1; ++r) {
        float v = bf2f(x[(size_t)r * HC + j]);
        s += v;
        s2 += v * v;
    }
    atomicAdd(&sums[j], s);
    atomicAdd(&sumsq[j], s2);
}

__global__ void bn_apply_kernel(const u16* __restrict__ x, u16* __restrict__ y,
                                const float* __restrict__ sums, const float* __restrict__ sumsq,
                                const float* __restrict__ g, const float* __restrict__ beta) {
    int t = blockIdx.x * blockDim.x + threadIdx.x;  // over N*HC/4
    if (t >= NNODES * HC / 4) return;
    int j = (t * 4) & (HC - 1);
    ushort4 xv = *(const ushort4*)&x[(size_t)t * 4];
    ushort4 o;
#pragma unroll
    for (int i = 0; i < 4; ++i) {
        float mu = sums[j + i] * (1.f / NNODES);
        float var = sumsq[j + i] * (1.f / NNODES) - mu * mu;
        float v = bf2f(((const u16*)&xv)[i]);
        ((u16*)&o)[i] = f2bf((v - mu) * rsqrtf(var + BN_EPS) * g[j + i] + beta[j + i]);
    }
    *(ushort4*)&y[(size_t)t * 4] = o;
}

// ---------------- log_softmax over 64 cols: one wave per row ----------------

__global__ void logsoftmax_kernel(const float* __restrict__ emb, float* __restrict__ out) {
    int row = blockIdx.x * 4 + (threadIdx.x >> 6);
    int lane = threadIdx.x & 63;
    float v = emb[(size_t)row * OUTDIM + lane];
    float m = v;
    for (int off = 32; off > 0; off >>= 1) m = fmaxf(m, __shfl_xor(m, off, 64));
    float e = expf(v - m);
    float s = e;
    for (int off = 32; off > 0; off >>= 1) s += __shfl_xor(s, off, 64);
    out[(size_t)row * OUTDIM + lane] = v - m - logf(s);
}

// ---------------- launch ----------------

extern "C" void kernel_launch(void* const* d_in, const int* in_sizes, int n_in,
                              void* d_out, int out_size, void* d_ws, size_t ws_size,
                              hipStream_t stream) {
    const float* x   = (const float*)d_in[0];
    const int*   ei  = (const int*)d_in[1];
    const float* W1  = (const float*)d_in[2];
    const float* at_s1 = (const float*)d_in[3];
    const float* at_d1 = (const float*)d_in[4];
    const float* b1  = (const float*)d_in[5];
    const float* W2  = (const float*)d_in[6];
    const float* at_s2 = (const float*)d_in[7];
    const float* at_d2 = (const float*)d_in[8];
    const float* b2  = (const float*)d_in[9];
    const float* g1  = (const float*)d_in[10];
    const float* be1 = (const float*)d_in[11];
    const float* g2  = (const float*)d_in[12];
    const float* be2 = (const float*)d_in[13];
    const float* Wl  = (const float*)d_in[14];
    const float* bl  = (const float*)d_in[15];

    float* out = (float*)d_out;                        // [N, 64] log_softmax
    float* emb = out + (size_t)NNODES * OUTDIM;        // [N, 64] emb

    char* ws = (char*)d_ws;
    size_t off = 0;
    auto alloc = [&](size_t bytes) {
        void* p = ws + off;
        off += (bytes + 255) & ~(size_t)255;
        return p;
    };
    int*   cnt     = (int*)alloc((size_t)NNODES * 4);
    int*   row_off = (int*)alloc((size_t)(NNODES + 1) * 4);
    int*   nxt     = (int*)alloc((size_t)NNODES * 4);
    int*   bsums   = (int*)alloc(64 * 4);
    int*   csr_src = (int*)alloc((size_t)ETOT * 4);
    float* asrc    = (float*)alloc((size_t)NNODES * 4 * 4);
    float* adst    = (float*)alloc((size_t)NNODES * 4 * 4);
    u16*   x_bf    = (u16*)alloc((size_t)NNODES * HC * 2);
    u16*   xh_bf   = (u16*)alloc((size_t)NNODES * HC * 2);
    u16*   ag_bf   = (u16*)alloc((size_t)NNODES * HC * 2);
    u16*   h_bf    = (u16*)alloc((size_t)NNODES * HC * 2);
    u16*   w1t     = (u16*)alloc((size_t)HC * INDIM * 2);
    u16*   w2t     = (u16*)alloc((size_t)HC * HC * 2);
    u16*   wlt     = (u16*)alloc((size_t)OUTDIM * HC * 2);
    float* bnsum   = (float*)alloc(HC * 4);
    float* bnsq    = (float*)alloc(HC * 4);

    const int scanBlocks = (NNODES + 4095) / 4096;
    const int eBlocks = (ETOT + 255) / 256;

    // ---- CSR build ----
    hipMemsetAsync(cnt, 0, (size_t)NNODES * 4, stream);
    hist_kernel<<<eBlocks, 256, 0, stream>>>(ei, cnt);
    scan1_kernel<<<scanBlocks, 256, 0, stream>>>(cnt, row_off, bsums);
    scan2_kernel<<<scanBlocks, 256, 0, stream>>>(row_off, bsums, nxt);
    fill_csr_kernel<<<eBlocks, 256, 0, stream>>>(ei, nxt, csr_src);

    // ---- casts ----
    castx_kernel<<<(NNODES * HC / 4 + 255) / 256, 256, 0, stream>>>(x, x_bf, NNODES * HC / 4);
    wcast_kernel<<<(INDIM * HC + 255) / 256, 256, 0, stream>>>(W1, w1t, INDIM, HC);
    wcast_kernel<<<(HC * HC + 255) / 256, 256, 0, stream>>>(W2, w2t, HC, HC);
    wcast_kernel<<<(HC * OUTDIM + 255) / 256, 256, 0, stream>>>(Wl, wlt, HC, OUTDIM);

    dim3 gemmGrid(2, (NNODES + 127) / 128);
    dim3 gemmGrid3(1, (NNODES + 127) / 128);
    int nhBlocks = (NNODES * HEADS + 255) / 256;
    int vecBlocks = (NNODES * HC / 4 + 255) / 256;
    int statBlocks = (NNODES + 127) / 128;

    // ---- Layer 1 ----
    gemm_bf16_kernel<<<gemmGrid, 256, 0, stream>>>(x_bf, w1t, xh_bf, nullptr, nullptr,
                                                   NNODES, HC, INDIM);
    alpha_kernel<<<nhBlocks, 256, 0, stream>>>(xh_bf, at_s1, at_d1, asrc, adst);
    aggregate_kernel<<<NNODES / 4, 256, 0, stream>>>(row_off, csr_src, asrc, adst, xh_bf, b1, ag_bf);
    hipMemsetAsync(bnsum, 0, HC * 4, stream);
    hipMemsetAsync(bnsq, 0, HC * 4, stream);
    bn_stats_kernel<<<statBlocks, HC, 0, stream>>>(ag_bf, bnsum, bnsq);
    bn_apply_kernel<<<vecBlocks, 256, 0, stream>>>(ag_bf, h_bf, bnsum, bnsq, g1, be1);

    // ---- Layer 2 ----
    gemm_bf16_kernel<<<gemmGrid, 256, 0, stream>>>(h_bf, w2t, xh_bf, nullptr, nullptr,
                                                   NNODES, HC, HC);
    alpha_kernel<<<nhBlocks, 256, 0, stream>>>(xh_bf, at_s2, at_d2, asrc, adst);
    aggregate_kernel<<<NNODES / 4, 256, 0, stream>>>(row_off, csr_src, asrc, adst, xh_bf, b2, ag_bf);
    hipMemsetAsync(bnsum, 0, HC * 4, stream);
    hipMemsetAsync(bnsq, 0, HC * 4, stream);
    bn_stats_kernel<<<statBlocks, HC, 0, stream>>>(ag_bf, bnsum, bnsq);
    bn_apply_kernel<<<vecBlocks, 256, 0, stream>>>(ag_bf, h_bf, bnsum, bnsq, g2, be2);

    // ---- Final linear + log_softmax ----
    gemm_bf16_kernel<<<gemmGrid3, 256, 0, stream>>>(h_bf, wlt, nullptr, emb, bl,
                                                    NNODES, OUTDIM, HC);
    logsoftmax_kernel<<<NNODES / 4, 256, 0, stream>>>(emb, out);
}